// Round 1
// baseline (961.781 us; speedup 1.0000x reference)
//
#include <hip/hip_runtime.h>
#include <stdint.h>
#include <math.h>

typedef unsigned int u32;
typedef unsigned long long u64;

#define HS_ 50
#define WS_ 64
#define AN_ 9
#define NN_ (HS_*WS_*AN_)      // 28800
#define MM_ 64
#define BB_ 16
#define XROW_ 25
#define FWORDS_ ((NN_+31)/32)  // 900
#define POS_CAP_ 128u
#define BATCH_ 256u
#define FG_T_ 0.7f
#define BG_T_ 0.3f

// ---------------- threefry2x32 (JAX-exact) ----------------
__device__ __forceinline__ u32 rotl32(u32 v, u32 r){ return (v<<r)|(v>>(32u-r)); }

__device__ __forceinline__ void tf2x32(u32 k0, u32 k1, u32 x0, u32 x1, u32& y0, u32& y1){
  u32 ks2 = k0 ^ k1 ^ 0x1BD11BDAu;
  x0 += k0; x1 += k1;
#define TFR(r) { x0 += x1; x1 = rotl32(x1,(r)); x1 ^= x0; }
  TFR(13) TFR(15) TFR(26) TFR(6)   x0 += k1;  x1 += ks2 + 1u;
  TFR(17) TFR(29) TFR(16) TFR(24)  x0 += ks2; x1 += k0  + 2u;
  TFR(13) TFR(15) TFR(26) TFR(6)   x0 += k0;  x1 += k1  + 3u;
  TFR(17) TFR(29) TFR(16) TFR(24)  x0 += k1;  x1 += ks2 + 4u;
  TFR(13) TFR(15) TFR(26) TFR(6)   x0 += ks2; x1 += k0  + 5u;
#undef TFR
  y0 = x0; y1 = x1;
}

// partitionable (fold-like) key derivation:
// keys = split(key(42), 16): key_b = cipher(root; 0, b)  (both words)
// k1,k2 = split(key_b):      k1 = cipher(key_b; 0,0), k2 = cipher(key_b; 0,1)
__device__ __forceinline__ void image_keys(int b, u32& k10,u32& k11,u32& k20,u32& k21){
  u32 r0, r1;
  tf2x32(0u, 42u, 0u, (u32)b, r0, r1);
  tf2x32(r0, r1, 0u, 0u, k10, k11);
  tf2x32(r0, r1, 0u, 1u, k20, k21);
}

// ---------------- anchors (bit-exact vs numpy build_anchors) ----------------
__device__ __forceinline__ void anchor_box(int i, float& ox1, float& oy1, float& ox2, float& oy2){
  #pragma clang fp contract(off)
  int a = i % AN_;
  int w = (i / AN_) % WS_;
  int h = i / (AN_ * WS_);
  const double sc[3] = {128.0, 256.0, 512.0};
  const double rt[3] = {0.5, 1.0, 2.0};
  double s = sc[a/3], r = rt[a%3];
  double sq = sqrt(r);
  float aw = (float)(s * sq);   // matches np: float32(s*sqrt(r)) from float64
  float ah = (float)(s / sq);
  float cx = ((float)w + 0.5f) * 16.0f;
  float cy = ((float)h + 0.5f) * 16.0f;
  float hx = aw * 0.5f;  // a/2.0 exact
  float hy = ah * 0.5f;
  float X1 = (cx - hx) / 1024.0f;
  float Y1 = (cy - hy) / 800.0f;
  float X2 = (cx + hx) / 1024.0f;
  float Y2 = (cy + hy) / 800.0f;
  bool valid = (X1 > 0.0f) && (Y1 > 0.0f) && (X2 < 1.0f) && (Y2 < 1.0f);
  ox1 = valid ? X1 : 0.0f;
  oy1 = valid ? Y1 : 0.0f;
  ox2 = valid ? X2 : 0.0f;
  oy2 = valid ? Y2 : 0.0f;
}

// ---------------- K1: IoU, matched max/argmax, per-gt best ----------------
__global__ __launch_bounds__(256) void k_iou(const float* __restrict__ x,
                                             float* __restrict__ miou,
                                             unsigned char* __restrict__ midx,
                                             u64* __restrict__ bestkey){
  #pragma clang fp contract(off)
  int b = blockIdx.y;
  int tid = threadIdx.x;
  __shared__ float g[MM_][4];
  __shared__ u64 bl[MM_];
  // 64 gts x 4 coords = 256 loads (x[..., 21..24])
  g[tid>>2][tid&3] = x[b*MM_*XROW_ + (tid>>2)*XROW_ + 21 + (tid&3)];
  if (tid < MM_) bl[tid] = 0ull;
  __syncthreads();

  int i = blockIdx.x*256 + tid;
  if (i < NN_){
    float ax1,ay1,ax2,ay2;
    anchor_box(i, ax1,ay1,ax2,ay2);
    float area_a = (ax2-ax1)*(ay2-ay1);
    float best = -1.0f; int bj = 0;
    for (int j = 0; j < MM_; ++j){
      float g0=g[j][0], g1=g[j][1], g2=g[j][2], g3=g[j][3];
      float ix1 = fmaxf(ax1,g0), iy1 = fmaxf(ay1,g1);
      float ix2 = fminf(ax2,g2), iy2 = fminf(ay2,g3);
      float iw = fmaxf(ix2-ix1, 0.0f), ih = fmaxf(iy2-iy1, 0.0f);
      float inter = iw*ih;
      float area_g = (g2-g0)*(g3-g1);
      float den = area_a + area_g;   // exact op order of reference, no FMA
      den = den - inter;
      den = den + 1e-7f;
      float iou = inter / den;
      if (iou > best){ best = iou; bj = j; }           // first-max (argmax) semantics
      // per-gt argmax over anchors, ties -> smaller anchor index
      u64 key = ((u64)__float_as_uint(iou) << 32) | (u64)(0xFFFFFFFFu - (u32)i);
      if (key > bl[j]) atomicMax(&bl[j], key);
    }
    miou[b*NN_ + i] = best;
    midx[b*NN_ + i] = (unsigned char)bj;
  }
  __syncthreads();
  if (tid < MM_ && bl[tid] != 0ull) atomicMax(&bestkey[b*MM_ + tid], bl[tid]);
}

// ---------------- K2: forced scatter ----------------
__global__ void k_forced(const u64* __restrict__ bestkey, u32* __restrict__ forced){
  int b = blockIdx.x, j = threadIdx.x;
  u64 key = bestkey[b*MM_ + j];
  if ((u32)(key >> 32) != 0u){  // best_iou > 0
    u32 i = 0xFFFFFFFFu - (u32)(key & 0xFFFFFFFFull);
    atomicOr(&forced[b*FWORDS_ + (i>>5)], 1u << (i & 31));
  }
}

// ---------------- K3: PRNG + candidate values + counts ----------------
__global__ __launch_bounds__(256) void k_rand(const float* __restrict__ miou,
                                              const u32* __restrict__ forced,
                                              u32* __restrict__ rpv,
                                              u32* __restrict__ rnv,
                                              u32* __restrict__ counts){
  int b = blockIdx.y, tid = threadIdx.x;
  int i = blockIdx.x*256 + tid;
  __shared__ u32 sc[2];
  if (tid < 2) sc[tid] = 0;
  __syncthreads();
  u32 lp = 0, ln = 0;
  if (i < NN_){
    u32 k10,k11,k20,k21;
    image_keys(b, k10,k11,k20,k21);
    u32 a0,a1,b0,b1;
    tf2x32(k10,k11, 0u, (u32)i, a0,a1);
    tf2x32(k20,k21, 0u, (u32)i, b0,b1);
    u32 pbits = a0 ^ a1;   // partitionable 32-bit draw
    u32 nbits = b0 ^ b1;
    float mi = miou[b*NN_ + i];
    bool fb = (forced[b*FWORDS_ + (i>>5)] >> (i & 31)) & 1u;
    bool pc = (mi > FG_T_) || fb;
    bool nc = (mi < BG_T_);
    // ranking value: (bits>>9)+1 is strictly order-isomorphic to uniform float; 0 = sentinel
    rpv[b*NN_ + i] = pc ? ((pbits >> 9) + 1u) : 0u;
    rnv[b*NN_ + i] = nc ? ((nbits >> 9) + 1u) : 0u;
    lp = pc; ln = nc;
  }
  atomicAdd(&sc[0], lp); atomicAdd(&sc[1], ln);
  __syncthreads();
  if (tid == 0){ atomicAdd(&counts[b*2+0], sc[0]); atomicAdd(&counts[b*2+1], sc[1]); }
}

// ---------------- K4: top-K threshold (value, then index tie-cut) ----------------
__global__ __launch_bounds__(256) void k_select(const u32* __restrict__ rpv,
                                                const u32* __restrict__ rnv,
                                                const u32* __restrict__ counts,
                                                u32* __restrict__ selp){
  int cls = blockIdx.x;   // 0 = pos, 1 = neg
  int b = blockIdx.y;
  int tid = threadIdx.x;
  u32 posc = counts[b*2+0], negc = counts[b*2+1];
  u32 npos = min(posc, POS_CAP_);
  u32 K   = (cls == 0) ? npos : (BATCH_ - npos);
  u32 cnt = (cls == 0) ? posc : negc;
  const u32* v = ((cls == 0) ? rpv : rnv) + (size_t)b*NN_;
  __shared__ u32 sc;

  if (cnt <= K){
    if (tid == 0){ selp[(b*2+cls)*2+0] = 0u; selp[(b*2+cls)*2+1] = 0xFFFFFFFFu; }
    return;
  }
  // binary search: largest vstar with count(val >= vstar) >= K
  u32 lo = 1u, hi = 1u << 23;
  while (lo < hi){
    u32 mid = lo + (hi - lo + 1u)/2u;
    if (tid == 0) sc = 0;
    __syncthreads();
    u32 c = 0;
    for (int i = tid; i < NN_; i += 256) c += (v[i] >= mid);
    atomicAdd(&sc, c);
    __syncthreads();
    u32 tot = sc;
    __syncthreads();
    if (tot >= K) lo = mid; else hi = mid - 1u;
  }
  u32 vstar = lo;
  // count strictly greater
  if (tid == 0) sc = 0;
  __syncthreads();
  { u32 c = 0; for (int i = tid; i < NN_; i += 256) c += (v[i] > vstar); atomicAdd(&sc, c); }
  __syncthreads();
  u32 cgt = sc;
  __syncthreads();
  u32 m = K - cgt;   // >= 1: take the m smallest indices among ties
  u32 l2 = 0, h2 = NN_ - 1;
  while (l2 < h2){
    u32 mid = (l2 + h2)/2u;
    if (tid == 0) sc = 0;
    __syncthreads();
    u32 c = 0;
    for (int i = tid; i < NN_; i += 256) c += (v[i] == vstar && (u32)i <= mid);
    atomicAdd(&sc, c);
    __syncthreads();
    u32 tot = sc;
    __syncthreads();
    if (tot >= m) h2 = mid; else l2 = mid + 1u;
  }
  if (tid == 0){ selp[(b*2+cls)*2+0] = vstar; selp[(b*2+cls)*2+1] = l2; }
}

// ---------------- K5: final cls + encoded offsets ----------------
__global__ __launch_bounds__(256) void k_out(const float* __restrict__ x,
                                             const unsigned char* __restrict__ midx,
                                             const u32* __restrict__ rpv,
                                             const u32* __restrict__ rnv,
                                             const u32* __restrict__ selp,
                                             float* __restrict__ out){
  #pragma clang fp contract(off)
  int b = blockIdx.y, tid = threadIdx.x;
  __shared__ float g[MM_][4];
  g[tid>>2][tid&3] = x[b*MM_*XROW_ + (tid>>2)*XROW_ + 21 + (tid&3)];
  __syncthreads();
  int i = blockIdx.x*256 + tid;
  if (i >= NN_) return;

  u32 pth = selp[(b*2+0)*2+0], pcut = selp[(b*2+0)*2+1];
  u32 nth = selp[(b*2+1)*2+0], ncut = selp[(b*2+1)*2+1];
  u32 pv = rpv[b*NN_ + i], nv = rnv[b*NN_ + i];
  bool selpos = (pv > 0u) && (pv > pth || (pv == pth && (u32)i <= pcut));
  bool selneg = (nv > 0u) && (nv > nth || (nv == nth && (u32)i <= ncut));
  float cls = selpos ? 1.0f : -1.0f;
  if (selneg) cls = 0.0f;   // sel_neg overrides (reference order)

  float tx = 0.0f, ty = 0.0f, tw = 0.0f, th = 0.0f;
  if (selpos){
    int j = midx[b*NN_ + i];
    float g0=g[j][0], g1=g[j][1], g2=g[j][2], g3=g[j][3];
    float ax1,ay1,ax2,ay2;
    anchor_box(i, ax1,ay1,ax2,ay2);
    float wgt = g2-g0, hgt = g3-g1;
    float xcg = (g2+g0)*0.5f, ycg = (g3+g1)*0.5f;
    float wr = ax2-ax1, hr = ay2-ay1;
    float xcr = (ax2+ax1)*0.5f, ycr = (ay2+ay1)*0.5f;
    float wrs = (wr > 0.0f) ? wr : 1.0f;
    float hrs = (hr > 0.0f) ? hr : 1.0f;
    tx = (wgt > 0.0f) ? (xcg - xcr)/wrs : 0.0f;
    ty = (hgt > 0.0f) ? (ycg - ycr)/hrs : 0.0f;
    tw = (wgt > 0.0f) ? logf(wgt/wrs) : 0.0f;
    th = (hgt > 0.0f) ? logf(hgt/hrs) : 0.0f;
  }
  float* o = out + (size_t)(b*NN_ + i)*5;
  o[0] = cls; o[1] = tx; o[2] = ty; o[3] = tw; o[4] = th;
}

extern "C" void kernel_launch(void* const* d_in, const int* in_sizes, int n_in,
                              void* d_out, int out_size, void* d_ws, size_t ws_size,
                              hipStream_t stream) {
  const float* x = (const float*)d_in[0];
  float* out = (float*)d_out;
  char* ws = (char*)d_ws;

  // workspace layout (zero-init region first)
  u64* bestkey = (u64*)ws;                                   // 16*64*8      = 8192
  u32* forced  = (u32*)(ws + 8192);                          // 16*900*4     = 57600
  u32* counts  = (u32*)(ws + 8192 + 57600);                  // 16*2*4       = 128
  u32* selp    = (u32*)(ws + 8192 + 57600 + 128);            // 16*2*2*4     = 256
  size_t off = 8192 + 57600 + 128 + 256;                     // 66176
  float* miou = (float*)(ws + off);          off += (size_t)BB_*NN_*4;
  unsigned char* midx = (unsigned char*)(ws + off); off += (size_t)BB_*NN_;
  u32* rpv = (u32*)(ws + off);               off += (size_t)BB_*NN_*4;
  u32* rnv = (u32*)(ws + off);               off += (size_t)BB_*NN_*4;
  (void)off; (void)ws_size; (void)in_sizes; (void)n_in; (void)out_size;

  hipMemsetAsync(d_ws, 0, 8192 + 57600 + 128, stream);  // bestkey, forced, counts

  dim3 gA((NN_ + 255)/256, BB_);
  k_iou   <<<gA, 256, 0, stream>>>(x, miou, midx, bestkey);
  k_forced<<<dim3(BB_), dim3(MM_), 0, stream>>>(bestkey, forced);
  k_rand  <<<gA, 256, 0, stream>>>(miou, forced, rpv, rnv, counts);
  k_select<<<dim3(2, BB_), 256, 0, stream>>>(rpv, rnv, counts, selp);
  k_out   <<<gA, 256, 0, stream>>>(x, midx, rpv, rnv, selp, out);
}

// Round 2
// 144.040 us; speedup vs baseline: 6.6772x; 6.6772x over previous
//
#include <hip/hip_runtime.h>
#include <stdint.h>
#include <math.h>

typedef unsigned int u32;
typedef unsigned long long u64;

#define HS_ 50
#define WS_ 64
#define AN_ 9
#define NN_ (HS_*WS_*AN_)      // 28800 (divisible by 64 -> wave-uniform validity)
#define MM_ 64
#define BB_ 16
#define XROW_ 25
#define FWORDS_ ((NN_+31)/32)  // 900
#define POS_CAP_ 128u
#define BATCH_ 256u
#define FG_T_ 0.7f
#define BG_T_ 0.3f

struct Keys { u32 k[BB_][4]; };   // per-image (k1.0,k1.1,k2.0,k2.1)

// ---------------- threefry2x32 (JAX-exact), host+device ----------------
__host__ __device__ __forceinline__ u32 rotl32(u32 v, u32 r){ return (v<<r)|(v>>(32u-r)); }

__host__ __device__ __forceinline__ void tf2x32(u32 k0, u32 k1, u32 x0, u32 x1, u32& y0, u32& y1){
  u32 ks2 = k0 ^ k1 ^ 0x1BD11BDAu;
  x0 += k0; x1 += k1;
#define TFR(r) { x0 += x1; x1 = rotl32(x1,(r)); x1 ^= x0; }
  TFR(13) TFR(15) TFR(26) TFR(6)   x0 += k1;  x1 += ks2 + 1u;
  TFR(17) TFR(29) TFR(16) TFR(24)  x0 += ks2; x1 += k0  + 2u;
  TFR(13) TFR(15) TFR(26) TFR(6)   x0 += k0;  x1 += k1  + 3u;
  TFR(17) TFR(29) TFR(16) TFR(24)  x0 += k1;  x1 += ks2 + 4u;
  TFR(13) TFR(15) TFR(26) TFR(6)   x0 += ks2; x1 += k0  + 5u;
#undef TFR
  y0 = x0; y1 = x1;
}

// ---------------- anchors (bit-exact vs numpy build_anchors) ----------------
__device__ __forceinline__ void anchor_box(int i, float& ox1, float& oy1, float& ox2, float& oy2){
  #pragma clang fp contract(off)
  int a = i % AN_;
  int w = (i / AN_) % WS_;
  int h = i / (AN_ * WS_);
  const double sc[3] = {128.0, 256.0, 512.0};
  const double rt[3] = {0.5, 1.0, 2.0};
  double s = sc[a/3], r = rt[a%3];
  double sq = sqrt(r);
  float aw = (float)(s * sq);
  float ah = (float)(s / sq);
  float cx = ((float)w + 0.5f) * 16.0f;
  float cy = ((float)h + 0.5f) * 16.0f;
  float hx = aw * 0.5f;
  float hy = ah * 0.5f;
  float X1 = (cx - hx) / 1024.0f;
  float Y1 = (cy - hy) / 800.0f;
  float X2 = (cx + hx) / 1024.0f;
  float Y2 = (cy + hy) / 800.0f;
  bool valid = (X1 > 0.0f) && (Y1 > 0.0f) && (X2 < 1.0f) && (Y2 < 1.0f);
  ox1 = valid ? X1 : 0.0f;
  oy1 = valid ? Y1 : 0.0f;
  ox2 = valid ? X2 : 0.0f;
  oy2 = valid ? Y2 : 0.0f;
}

// ---------------- K1: IoU, matched max/argmax, per-gt best (atomic-free inner loop) ----------------
__global__ __launch_bounds__(256) void k_iou(const float* __restrict__ x,
                                             float* __restrict__ miou,
                                             unsigned char* __restrict__ midx,
                                             u64* __restrict__ bestkey){
  #pragma clang fp contract(off)
  int b = blockIdx.y;
  int tid = threadIdx.x;
  int wid = tid >> 6, lane = tid & 63;
  __shared__ float g[MM_][4];
  __shared__ u64 wl[4][MM_];
  g[tid>>2][tid&3] = x[b*MM_*XROW_ + (tid>>2)*XROW_ + 21 + (tid&3)];
  for (int j = tid; j < 4*MM_; j += 256) ((u64*)wl)[j] = 0ull;
  __syncthreads();

  int i = blockIdx.x*256 + tid;
  if (i < NN_){                                     // wave-uniform (NN_ % 64 == 0)
    float ax1,ay1,ax2,ay2;
    anchor_box(i, ax1,ay1,ax2,ay2);
    bool av = (ax2 > 0.0f);
    if (__ballot(av) == 0ull){
      // whole wave invalid: iou == 0 for every gt -> matched_iou=0, argmax=0
      miou[b*NN_ + i] = 0.0f;
      midx[b*NN_ + i] = 0;
    } else {
      float area_a = (ax2-ax1)*(ay2-ay1);
      float best = -1.0f; int bj = 0;
      for (int j = 0; j < MM_; ++j){
        float g0=g[j][0], g1=g[j][1], g2=g[j][2], g3=g[j][3];
        float ix1 = fmaxf(ax1,g0), iy1 = fmaxf(ay1,g1);
        float ix2 = fminf(ax2,g2), iy2 = fminf(ay2,g3);
        float iw = fmaxf(ix2-ix1, 0.0f), ih = fmaxf(iy2-iy1, 0.0f);
        float inter = iw*ih;
        float area_g = (g2-g0)*(g3-g1);
        float den = area_a + area_g;   // exact reference op order, no FMA
        den = den - inter;
        den = den + 1e-7f;
        float iou = inter / den;
        if (iou > best){ best = iou; bj = j; }       // first-max semantics
        // wave-level per-gt max (iou >= 0 -> bit pattern order-isomorphic)
        u32 ib = __float_as_uint(iou);
        u32 mx = ib;
        #pragma unroll
        for (int off = 32; off >= 1; off >>= 1)
          mx = max(mx, (u32)__shfl_xor((int)mx, off, 64));
        if (mx){
          u64 who = __ballot(ib == mx);
          int win = __ffsll((long long)who) - 1;     // lowest lane = smallest i
          if (lane == win)
            wl[wid][j] = ((u64)mx << 32) | (u64)(0xFFFFFFFFu - (u32)i);
        }
      }
      miou[b*NN_ + i] = best;
      midx[b*NN_ + i] = (unsigned char)bj;
    }
  }
  __syncthreads();
  if (tid < MM_){
    u64 k0 = wl[0][tid], k1 = wl[1][tid], k2 = wl[2][tid], k3 = wl[3][tid];
    u64 kk = max(max(k0,k1), max(k2,k3));
    if (kk) atomicMax(&bestkey[b*MM_ + tid], kk);
  }
}

// ---------------- K2: forced scatter ----------------
__global__ void k_forced(const u64* __restrict__ bestkey, u32* __restrict__ forced){
  int b = blockIdx.x, j = threadIdx.x;
  u64 key = bestkey[b*MM_ + j];
  if ((u32)(key >> 32) != 0u){  // best_iou > 0
    u32 i = 0xFFFFFFFFu - (u32)(key & 0xFFFFFFFFull);
    atomicOr(&forced[b*FWORDS_ + (i>>5)], 1u << (i & 31));
  }
}

// ---------------- K3: PRNG + candidate values + counts ----------------
__global__ __launch_bounds__(256) void k_rand(const float* __restrict__ miou,
                                              const u32* __restrict__ forced,
                                              Keys keys,
                                              u32* __restrict__ rpv,
                                              u32* __restrict__ rnv,
                                              u32* __restrict__ counts){
  int b = blockIdx.y, tid = threadIdx.x;
  int lane = tid & 63;
  int i = blockIdx.x*256 + tid;
  __shared__ u32 sc[2];
  if (tid < 2) sc[tid] = 0;
  __syncthreads();
  bool pc = false, nc = false;
  if (i < NN_){
    u32 a0,a1,b0,b1;
    tf2x32(keys.k[b][0], keys.k[b][1], 0u, (u32)i, a0,a1);
    tf2x32(keys.k[b][2], keys.k[b][3], 0u, (u32)i, b0,b1);
    u32 pbits = a0 ^ a1;
    u32 nbits = b0 ^ b1;
    float mi = miou[b*NN_ + i];
    bool fb = (forced[b*FWORDS_ + (i>>5)] >> (i & 31)) & 1u;
    pc = (mi > FG_T_) || fb;
    nc = (mi < BG_T_);
    rpv[b*NN_ + i] = pc ? ((pbits >> 9) + 1u) : 0u;
    rnv[b*NN_ + i] = nc ? ((nbits >> 9) + 1u) : 0u;
  }
  u64 bp = __ballot(pc), bn = __ballot(nc);
  if (lane == 0){
    if (bp) atomicAdd(&sc[0], (u32)__popcll(bp));
    if (bn) atomicAdd(&sc[1], (u32)__popcll(bn));
  }
  __syncthreads();
  if (tid == 0){
    if (sc[0]) atomicAdd(&counts[b*2+0], sc[0]);
    if (sc[1]) atomicAdd(&counts[b*2+1], sc[1]);
  }
}

// ---------------- K4: radix-select top-K threshold ----------------
#define HB1 4096
#define HB2 2048
__global__ __launch_bounds__(256) void k_select(const u32* __restrict__ rpv,
                                                const u32* __restrict__ rnv,
                                                const u32* __restrict__ counts,
                                                u32* __restrict__ selp){
  int cls = blockIdx.x;   // 0 = pos, 1 = neg
  int b = blockIdx.y;
  int tid = threadIdx.x;
  __shared__ u32 hist[HB1];
  __shared__ u32 ts[256], suf[256];
  __shared__ u32 bc[8];
  __shared__ u32 tielist[256];
  __shared__ u32 tiecnt;

  u32 posc = counts[b*2+0], negc = counts[b*2+1];
  u32 npos = min(posc, POS_CAP_);
  u32 K   = (cls == 0) ? npos : (BATCH_ - npos);
  u32 cnt = (cls == 0) ? posc : negc;
  const u32* v = ((cls == 0) ? rpv : rnv) + (size_t)b*NN_;

  if (cnt <= K){
    if (tid == 0){ selp[(b*2+cls)*2+0] = 0u; selp[(b*2+cls)*2+1] = 0xFFFFFFFFu; }
    return;
  }
  // phase 1: histogram of high 12 bits of (v-1)
  for (int h = tid; h < HB1; h += 256) hist[h] = 0;
  __syncthreads();
  for (int i = tid; i < NN_; i += 256){ u32 xv = v[i]; if (xv) atomicAdd(&hist[(xv-1u)>>11], 1u); }
  __syncthreads();
  { u32 s = 0; for (int q = 0; q < 16; ++q) s += hist[tid*16+q]; ts[tid] = s; }
  __syncthreads();
  if (tid == 0){ u32 acc = 0; for (int t = 255; t >= 0; --t){ suf[t] = acc; acc += ts[t]; } }
  __syncthreads();
  if (suf[tid] < K && suf[tid] + ts[tid] >= K){
    u32 acc = suf[tid]; int B = 0;
    for (int q = 15; q >= 0; --q){
      u32 hb = hist[tid*16+q];
      if (acc + hb >= K){ B = tid*16+q; break; }
      acc += hb;
    }
    bc[0] = (u32)B; bc[1] = K - acc; bc[2] = acc;  // bin, K' in bin, strictly-above count
  }
  __syncthreads();
  u32 B = bc[0], Kp = bc[1], SB = bc[2];
  // phase 2: histogram of low 11 bits within bin B
  for (int h = tid; h < HB2; h += 256) hist[h] = 0;
  __syncthreads();
  for (int i = tid; i < NN_; i += 256){
    u32 xv = v[i];
    if (xv && ((xv-1u)>>11) == B) atomicAdd(&hist[(xv-1u)&0x7FFu], 1u);
  }
  __syncthreads();
  { u32 s = 0; for (int q = 0; q < 8; ++q) s += hist[tid*8+q]; ts[tid] = s; }
  __syncthreads();
  if (tid == 0){ u32 acc = 0; for (int t = 255; t >= 0; --t){ suf[t] = acc; acc += ts[t]; } }
  __syncthreads();
  if (suf[tid] < Kp && suf[tid] + ts[tid] >= Kp){
    u32 acc = suf[tid]; int L = 0;
    for (int q = 7; q >= 0; --q){
      u32 hb = hist[tid*8+q];
      if (acc + hb >= Kp){ L = tid*8+q; break; }
      acc += hb;
    }
    bc[3] = (u32)L; bc[4] = Kp - acc; bc[5] = hist[L];   // low bin, m, multiplicity
  }
  __syncthreads();
  u32 L = bc[3], m = bc[4], mult = bc[5];
  u32 vstar = ((B << 11) | L) + 1u;
  (void)SB;
  u32 cut;
  if (mult == m){
    cut = 0xFFFFFFFFu;               // all ties selected (common case m=mult=1)
  } else {
    if (tid == 0) tiecnt = 0;
    __syncthreads();
    for (int i = tid; i < NN_; i += 256){
      if (v[i] == vstar){ u32 p = atomicAdd(&tiecnt, 1u); if (p < 256) tielist[p] = (u32)i; }
    }
    __syncthreads();
    u32 n = min(tiecnt, 256u);
    if (tid < (int)n){
      u32 my = tielist[tid]; u32 r = 0;
      for (u32 t2 = 0; t2 < n; ++t2) r += (tielist[t2] < my);
      if (r == m - 1u) bc[6] = my;   // m-th smallest tie index
    }
    __syncthreads();
    cut = bc[6];
  }
  if (tid == 0){ selp[(b*2+cls)*2+0] = vstar; selp[(b*2+cls)*2+1] = cut; }
}

// ---------------- K5: final cls + encoded offsets ----------------
__global__ __launch_bounds__(256) void k_out(const float* __restrict__ x,
                                             const unsigned char* __restrict__ midx,
                                             const u32* __restrict__ rpv,
                                             const u32* __restrict__ rnv,
                                             const u32* __restrict__ selp,
                                             float* __restrict__ out){
  #pragma clang fp contract(off)
  int b = blockIdx.y, tid = threadIdx.x;
  __shared__ float g[MM_][4];
  g[tid>>2][tid&3] = x[b*MM_*XROW_ + (tid>>2)*XROW_ + 21 + (tid&3)];
  __syncthreads();
  int i = blockIdx.x*256 + tid;
  if (i >= NN_) return;

  u32 pth = selp[(b*2+0)*2+0], pcut = selp[(b*2+0)*2+1];
  u32 nth = selp[(b*2+1)*2+0], ncut = selp[(b*2+1)*2+1];
  u32 pv = rpv[b*NN_ + i], nv = rnv[b*NN_ + i];
  bool selpos = (pv > 0u) && (pv > pth || (pv == pth && (u32)i <= pcut));
  bool selneg = (nv > 0u) && (nv > nth || (nv == nth && (u32)i <= ncut));
  float cls = selpos ? 1.0f : -1.0f;
  if (selneg) cls = 0.0f;

  float tx = 0.0f, ty = 0.0f, tw = 0.0f, th = 0.0f;
  if (selpos){
    int j = midx[b*NN_ + i];
    float g0=g[j][0], g1=g[j][1], g2=g[j][2], g3=g[j][3];
    float ax1,ay1,ax2,ay2;
    anchor_box(i, ax1,ay1,ax2,ay2);
    float wgt = g2-g0, hgt = g3-g1;
    float xcg = (g2+g0)*0.5f, ycg = (g3+g1)*0.5f;
    float wr = ax2-ax1, hr = ay2-ay1;
    float xcr = (ax2+ax1)*0.5f, ycr = (ay2+ay1)*0.5f;
    float wrs = (wr > 0.0f) ? wr : 1.0f;
    float hrs = (hr > 0.0f) ? hr : 1.0f;
    tx = (wgt > 0.0f) ? (xcg - xcr)/wrs : 0.0f;
    ty = (hgt > 0.0f) ? (ycg - ycr)/hrs : 0.0f;
    tw = (wgt > 0.0f) ? logf(wgt/wrs) : 0.0f;
    th = (hgt > 0.0f) ? logf(hgt/hrs) : 0.0f;
  }
  float* o = out + (size_t)(b*NN_ + i)*5;
  o[0] = cls; o[1] = tx; o[2] = ty; o[3] = tw; o[4] = th;
}

extern "C" void kernel_launch(void* const* d_in, const int* in_sizes, int n_in,
                              void* d_out, int out_size, void* d_ws, size_t ws_size,
                              hipStream_t stream) {
  const float* x = (const float*)d_in[0];
  float* out = (float*)d_out;
  char* ws = (char*)d_ws;

  u64* bestkey = (u64*)ws;                                   // 8192
  u32* forced  = (u32*)(ws + 8192);                          // 57600
  u32* counts  = (u32*)(ws + 8192 + 57600);                  // 128
  u32* selp    = (u32*)(ws + 8192 + 57600 + 128);            // 256
  size_t off = 8192 + 57600 + 128 + 256;
  float* miou = (float*)(ws + off);          off += (size_t)BB_*NN_*4;
  unsigned char* midx = (unsigned char*)(ws + off); off += (size_t)BB_*NN_;
  u32* rpv = (u32*)(ws + off);               off += (size_t)BB_*NN_*4;
  u32* rnv = (u32*)(ws + off);               off += (size_t)BB_*NN_*4;
  (void)off; (void)ws_size; (void)in_sizes; (void)n_in; (void)out_size;

  // host-side JAX key derivation (partitionable threefry), deterministic
  Keys keys;
  for (int b = 0; b < BB_; ++b){
    u32 r0, r1;
    tf2x32(0u, 42u, 0u, (u32)b, r0, r1);
    tf2x32(r0, r1, 0u, 0u, keys.k[b][0], keys.k[b][1]);
    tf2x32(r0, r1, 0u, 1u, keys.k[b][2], keys.k[b][3]);
  }

  hipMemsetAsync(d_ws, 0, 8192 + 57600 + 128, stream);  // bestkey, forced, counts

  dim3 gA((NN_ + 255)/256, BB_);
  k_iou   <<<gA, 256, 0, stream>>>(x, miou, midx, bestkey);
  k_forced<<<dim3(BB_), dim3(MM_), 0, stream>>>(bestkey, forced);
  k_rand  <<<gA, 256, 0, stream>>>(miou, forced, keys, rpv, rnv, counts);
  k_select<<<dim3(2, BB_), 256, 0, stream>>>(rpv, rnv, counts, selp);
  k_out   <<<gA, 256, 0, stream>>>(x, midx, rpv, rnv, selp, out);
}